// Round 1
// baseline (359.199 us; speedup 1.0000x reference)
//
#include <hip/hip_runtime.h>
#include <stdint.h>

#define NHITS 100000
#define NOBJ  1024
#define DEMB  12
#define KCHUNK 256
#define HALF_HITS 50000
#define HALF_PAIRS 51200000u   // NHITS*NOBJ/2

// ---------------- ws layout (bytes) ----------------
// 0:   double v_att_sum
// 8:   double v_rep_sum
// 16:  double coward_sum
// 24:  double noise_sum
// 32:  ull    noise_cnt
// 40:  ull    n_rep
// 48:  float  freq (+ pad to 64)
// 64:  ull    packed[1024]                  (ends 8256)
// 8256: float x_a[1024*12]                  (ends 57408)
// 57408: float q_a[1024]                    (ends 61504)

__device__ inline uint32_t rotl32(uint32_t x, int n) {
    return (x << n) | (x >> (32 - n));
}

// JAX Threefry-2x32, 20 rounds. key = (k0, k1).
__device__ inline void threefry2x32(uint32_t k0, uint32_t k1,
                                    uint32_t x0, uint32_t x1,
                                    uint32_t& o0, uint32_t& o1) {
    uint32_t ks2 = k0 ^ k1 ^ 0x1BD11BDAu;
    x0 += k0; x1 += k1;
    // group A rotations {13,15,26,6}, group B {17,29,16,24}
#define TF_ROUND(r) { x0 += x1; x1 = rotl32(x1, r); x1 ^= x0; }
    TF_ROUND(13) TF_ROUND(15) TF_ROUND(26) TF_ROUND(6)
    x0 += k1;  x1 += ks2 + 1u;
    TF_ROUND(17) TF_ROUND(29) TF_ROUND(16) TF_ROUND(24)
    x0 += ks2; x1 += k0 + 2u;
    TF_ROUND(13) TF_ROUND(15) TF_ROUND(26) TF_ROUND(6)
    x0 += k0;  x1 += k1 + 3u;
    TF_ROUND(17) TF_ROUND(29) TF_ROUND(16) TF_ROUND(24)
    x0 += k1;  x1 += ks2 + 4u;
    TF_ROUND(13) TF_ROUND(15) TF_ROUND(26) TF_ROUND(6)
    x0 += ks2; x1 += k0 + 5u;
#undef TF_ROUND
    o0 = x0; o1 = x1;
}

__device__ inline double waveReduceD(double v) {
    for (int off = 32; off > 0; off >>= 1) v += __shfl_down(v, off, 64);
    return v;
}
__device__ inline unsigned int waveReduceU(unsigned int v) {
    for (int off = 32; off > 0; off >>= 1) v += __shfl_down(v, off, 64);
    return v;
}

// ---------------- kernels ----------------

__global__ void k_init(unsigned long long* packed, unsigned long long* hdr) {
    int t = blockIdx.x * blockDim.x + threadIdx.x;
    if (t < NOBJ) packed[t] = 0xFFFFFFFFull;   // q_bits=0, idx=0
    if (t < 8)    hdr[t] = 0ull;               // zero accumulators + freq
}

__global__ void k_hits(const float* __restrict__ beta,
                       const int* __restrict__ oid,
                       unsigned long long* __restrict__ packed,
                       double* __restrict__ noise_sum,
                       unsigned long long* __restrict__ noise_cnt) {
    int j = blockIdx.x * blockDim.x + threadIdx.x;
    float nb = 0.0f;
    unsigned int nc = 0;
    if (j < NHITS) {
        float b = beta[j];
        int o = oid[j];
        if (o > 0) {
            float a = atanhf(b);
            float q = a * a + 0.1f;
            unsigned long long p =
                ((unsigned long long)__float_as_uint(q) << 32) |
                (unsigned long long)(0xFFFFFFFFu - (unsigned)j);
            atomicMax(&packed[o - 1], p);
        } else {
            nb = b; nc = 1;
        }
    }
    double rb = waveReduceD((double)nb);
    unsigned int rc = waveReduceU(nc);
    if ((threadIdx.x & 63) == 0) {
        if (rb != 0.0) atomicAdd(noise_sum, rb);
        if (rc)        atomicAdd(noise_cnt, (unsigned long long)rc);
    }
}

__global__ void k_alphas(const unsigned long long* __restrict__ packed,
                         const float* __restrict__ x,
                         const float* __restrict__ beta,
                         float* __restrict__ x_a,
                         float* __restrict__ q_a,
                         double* __restrict__ coward_sum) {
    int k = blockIdx.x * blockDim.x + threadIdx.x;
    double c = 0.0;
    if (k < NOBJ) {
        unsigned idx = 0xFFFFFFFFu - (unsigned)(packed[k] & 0xFFFFFFFFull);
#pragma unroll
        for (int d = 0; d < DEMB; ++d) x_a[k * DEMB + d] = x[idx * DEMB + d];
        float b = beta[idx];
        float a = atanhf(b);
        q_a[k] = a * a + 0.1f;
        c = 1.0 - (double)b;
    }
    double rc = waveReduceD(c);
    if ((threadIdx.x & 63) == 0) atomicAdd(coward_sum, rc);
}

template <int PASS>
__global__ __launch_bounds__(256)
void k_pairs(const float* __restrict__ x,
             const float* __restrict__ beta,
             const int* __restrict__ oid,
             const float* __restrict__ x_a,
             const float* __restrict__ q_a,
             double* __restrict__ acc_out,
             unsigned long long* __restrict__ nrep_out,
             const float* __restrict__ freq_ptr) {
    __shared__ float sxa[KCHUNK * DEMB];
    __shared__ float sqa[KCHUNK];
    __shared__ float sa2[KCHUNK];
    const int kbase = blockIdx.y * KCHUNK;
    for (int i = threadIdx.x; i < KCHUNK * DEMB; i += 256)
        sxa[i] = x_a[kbase * DEMB + i];
    if (threadIdx.x < KCHUNK) sqa[threadIdx.x] = q_a[kbase + threadIdx.x];
    __syncthreads();
    if (threadIdx.x < KCHUNK) {
        float s = 0.f;
#pragma unroll
        for (int d = 0; d < DEMB; ++d) {
            float a = sxa[threadIdx.x * DEMB + d];
            s = fmaf(a, a, s);
        }
        sa2[threadIdx.x] = s;
    }
    __syncthreads();

    int t = blockIdx.x * blockDim.x + threadIdx.x;
    bool valid = t < HALF_HITS;
    int j0 = t, j1 = t + HALF_HITS;
    float X0[DEMB], X1[DEMB];
    float q0 = 0.f, q1 = 0.f, xx0 = 0.f, xx1 = 0.f;
    int o0 = -1, o1 = -1;
    if (valid) {
#pragma unroll
        for (int d = 0; d < DEMB; ++d) {
            X0[d] = x[j0 * DEMB + d];
            X1[d] = x[j1 * DEMB + d];
        }
#pragma unroll
        for (int d = 0; d < DEMB; ++d) {
            xx0 = fmaf(X0[d], X0[d], xx0);
            xx1 = fmaf(X1[d], X1[d], xx1);
        }
        float b0 = beta[j0], b1 = beta[j1];
        float a0 = atanhf(b0), a1 = atanhf(b1);
        q0 = a0 * a0 + 0.1f;
        q1 = a1 * a1 + 0.1f;
        o0 = oid[j0];
        o1 = oid[j1];
    }
    float freq = 0.f;
    if (PASS == 2) freq = *freq_ptr;

    double acc = 0.0;
    unsigned int cnt = 0;
    if (valid) {
        for (int kk = 0; kk < KCHUNK; ++kk) {
            float dot0 = 0.f, dot1 = 0.f;
            const float* xa = &sxa[kk * DEMB];
#pragma unroll
            for (int d = 0; d < DEMB; ++d) {
                float a = xa[d];
                dot0 = fmaf(X0[d], a, dot0);
                dot1 = fmaf(X1[d], a, dot1);
            }
            int k = kbase + kk;
            float qa = sqa[kk];
            float a2 = sa2[kk];
            // match reference order: (xx - 2*dot) + xa2, clamped at 0
            float d2_0 = fmaxf((xx0 - 2.0f * dot0) + a2, 0.0f);
            float d2_1 = fmaxf((xx1 - 2.0f * dot1) + a2, 0.0f);
            bool att0 = (o0 == k + 1), att1 = (o1 == k + 1);
            if (PASS == 1) {
                // dist<1  <=>  d2<1  (sqrt monotone, clamp 1e-12 irrelevant)
                if (att0) acc += (double)(q0 * qa * d2_0);
                else if (d2_0 < 1.0f) cnt++;
                if (att1) acc += (double)(q1 * qa * d2_1);
                else if (d2_1 < 1.0f) cnt++;
            } else {
                bool rep0 = (!att0) && (d2_0 < 1.0f);
                bool rep1 = (!att1) && (d2_1 < 1.0f);
                if (rep0 | rep1) {
                    uint32_t f0 = (uint32_t)j0 * NOBJ + (uint32_t)k;
                    uint32_t b0, b1;
                    threefry2x32(0u, 42u, f0, f0 + HALF_PAIRS, b0, b1);
                    if (rep0) {
                        float u = __uint_as_float((b0 >> 9) | 0x3f800000u) - 1.0f;
                        if (u < freq) {
                            float dist0 = sqrtf(fmaxf(d2_0, 1e-12f));
                            acc += (double)(q0 * qa * (1.0f - dist0));
                        }
                    }
                    if (rep1) {
                        float u = __uint_as_float((b1 >> 9) | 0x3f800000u) - 1.0f;
                        if (u < freq) {
                            float dist1 = sqrtf(fmaxf(d2_1, 1e-12f));
                            acc += (double)(q1 * qa * (1.0f - dist1));
                        }
                    }
                }
            }
        }
    }
    double racc = waveReduceD(acc);
    if (PASS == 1) {
        unsigned int rc = waveReduceU(cnt);
        if ((threadIdx.x & 63) == 0) {
            if (racc != 0.0) atomicAdd(acc_out, racc);
            if (rc) atomicAdd(nrep_out, (unsigned long long)rc);
        }
    } else {
        if ((threadIdx.x & 63) == 0) {
            if (racc != 0.0) atomicAdd(acc_out, racc);
        }
    }
}

__global__ void k_freq(const unsigned long long* __restrict__ nrep,
                       float* __restrict__ freq) {
    unsigned long long n = *nrep;
    if (n < 1ull) n = 1ull;
    float f = 100000.0f / (float)n;   // f32 division, as in reference
    *freq = fminf(f, 1.0f);
}

__global__ void k_final(const double* __restrict__ accs,
                        const unsigned long long* __restrict__ noise_cnt,
                        const float* __restrict__ freq,
                        float* __restrict__ out) {
    double v_att = accs[0] / (double)NHITS;
    double v_rep = accs[1] / (double)(*freq) / (double)NHITS;
    double l_cow = accs[2] / (double)NOBJ;
    unsigned long long nc = *noise_cnt;
    if (nc < 1ull) nc = 1ull;
    double l_noise = accs[3] / ((double)nc + 1e-9);
    double loss = v_att + v_rep + l_cow + 0.1 * l_noise;
    out[0] = (float)v_att;
    out[1] = (float)v_rep;
    out[2] = (float)l_cow;
    out[3] = (float)l_noise;
    out[4] = (float)loss;
}

// ---------------- launcher ----------------

extern "C" void kernel_launch(void* const* d_in, const int* in_sizes, int n_in,
                              void* d_out, int out_size, void* d_ws, size_t ws_size,
                              hipStream_t stream) {
    const float* beta = (const float*)d_in[0];
    const float* x    = (const float*)d_in[1];
    const int*   oid  = (const int*)d_in[2];
    float* out = (float*)d_out;

    char* ws = (char*)d_ws;
    double* v_att_sum = (double*)(ws + 0);
    double* v_rep_sum = (double*)(ws + 8);
    double* coward_sum = (double*)(ws + 16);
    double* noise_sum = (double*)(ws + 24);
    unsigned long long* noise_cnt = (unsigned long long*)(ws + 32);
    unsigned long long* nrep = (unsigned long long*)(ws + 40);
    float* freq = (float*)(ws + 48);
    unsigned long long* packed = (unsigned long long*)(ws + 64);
    float* x_a = (float*)(ws + 8256);
    float* q_a = (float*)(ws + 57408);

    k_init<<<4, 256, 0, stream>>>(packed, (unsigned long long*)ws);
    k_hits<<<(NHITS + 255) / 256, 256, 0, stream>>>(beta, oid, packed,
                                                    noise_sum, noise_cnt);
    k_alphas<<<4, 256, 0, stream>>>(packed, x, beta, x_a, q_a, coward_sum);

    dim3 gpairs((HALF_HITS + 255) / 256, NOBJ / KCHUNK);
    k_pairs<1><<<gpairs, 256, 0, stream>>>(x, beta, oid, x_a, q_a,
                                           v_att_sum, nrep, nullptr);
    k_freq<<<1, 1, 0, stream>>>(nrep, freq);
    k_pairs<2><<<gpairs, 256, 0, stream>>>(x, beta, oid, x_a, q_a,
                                           v_rep_sum, nullptr, freq);
    k_final<<<1, 1, 0, stream>>>((double*)ws, noise_cnt, freq, out);
}

// Round 2
// 263.452 us; speedup vs baseline: 1.3634x; 1.3634x over previous
//
#include <hip/hip_runtime.h>
#include <stdint.h>

#define NHITS 100000
#define NOBJ  1024
#define DEMB  12
#define KCHUNK 32
#define HQ    25000          // hits per slot (4 slots/thread)
#define HALF_PAIRS 51200000u // NHITS*NOBJ/2

// ---------------- ws layout (bytes) ----------------
// 0:   double v_att_sum
// 8:   double v_rep_sum
// 16:  double coward_sum
// 24:  double noise_sum
// 32:  ull    noise_cnt
// 40:  ull    nrep_all      (all pairs d2<1, incl. attractive)
// 48:  ull    att_cnt       (attractive pairs with d2<1)
// 56:  float  freq
// 64:  ull    packed[1024]                  (64..8256)
// 8256: float4 xa4[1024*3]                  (8256..57408)
// 57408: float2 qa2[1024]   {q_a, a2}       (57408..65600)

__device__ inline uint32_t rotl32(uint32_t x, int n) {
    return (x << n) | (x >> (32 - n));
}

__device__ inline void threefry2x32(uint32_t k0, uint32_t k1,
                                    uint32_t x0, uint32_t x1,
                                    uint32_t& o0, uint32_t& o1) {
    uint32_t ks2 = k0 ^ k1 ^ 0x1BD11BDAu;
    x0 += k0; x1 += k1;
#define TF_ROUND(r) { x0 += x1; x1 = rotl32(x1, r); x1 ^= x0; }
    TF_ROUND(13) TF_ROUND(15) TF_ROUND(26) TF_ROUND(6)
    x0 += k1;  x1 += ks2 + 1u;
    TF_ROUND(17) TF_ROUND(29) TF_ROUND(16) TF_ROUND(24)
    x0 += ks2; x1 += k0 + 2u;
    TF_ROUND(13) TF_ROUND(15) TF_ROUND(26) TF_ROUND(6)
    x0 += k0;  x1 += k1 + 3u;
    TF_ROUND(17) TF_ROUND(29) TF_ROUND(16) TF_ROUND(24)
    x0 += k1;  x1 += ks2 + 4u;
    TF_ROUND(13) TF_ROUND(15) TF_ROUND(26) TF_ROUND(6)
    x0 += ks2; x1 += k0 + 5u;
#undef TF_ROUND
    o0 = x0; o1 = x1;
}

__device__ inline float tf_uniform(uint32_t bits) {
    return __uint_as_float((bits >> 9) | 0x3f800000u) - 1.0f;
}

__device__ inline double waveReduceD(double v) {
    for (int off = 32; off > 0; off >>= 1) v += __shfl_down(v, off, 64);
    return v;
}
__device__ inline unsigned int waveReduceU(unsigned int v) {
    for (int off = 32; off > 0; off >>= 1) v += __shfl_down(v, off, 64);
    return v;
}

#define DOT12(XA, XB, XC, A, B, C) \
    fmaf((XC).w, (C).w, fmaf((XC).z, (C).z, fmaf((XC).y, (C).y, fmaf((XC).x, (C).x, \
    fmaf((XB).w, (B).w, fmaf((XB).z, (B).z, fmaf((XB).y, (B).y, fmaf((XB).x, (B).x, \
    fmaf((XA).w, (A).w, fmaf((XA).z, (A).z, fmaf((XA).y, (A).y, (XA).x * (A).x)))))))))))

#define SS12(XA, XB, XC) DOT12(XA, XB, XC, XA, XB, XC)

// ---------------- kernels ----------------

__global__ void k_init(unsigned long long* packed, unsigned long long* hdr) {
    int t = blockIdx.x * blockDim.x + threadIdx.x;
    if (t < NOBJ) packed[t] = 0xFFFFFFFFull;
    if (t < 8)    hdr[t] = 0ull;
}

__global__ void k_hits(const float* __restrict__ beta,
                       const int* __restrict__ oid,
                       unsigned long long* __restrict__ packed,
                       double* __restrict__ noise_sum,
                       unsigned long long* __restrict__ noise_cnt) {
    int j = blockIdx.x * blockDim.x + threadIdx.x;
    float nb = 0.0f;
    unsigned int nc = 0;
    if (j < NHITS) {
        float b = beta[j];
        int o = oid[j];
        if (o > 0) {
            float a = atanhf(b);
            float q = a * a + 0.1f;
            unsigned long long p =
                ((unsigned long long)__float_as_uint(q) << 32) |
                (unsigned long long)(0xFFFFFFFFu - (unsigned)j);
            atomicMax(&packed[o - 1], p);
        } else {
            nb = b; nc = 1;
        }
    }
    double rb = waveReduceD((double)nb);
    unsigned int rc = waveReduceU(nc);
    if ((threadIdx.x & 63) == 0) {
        if (rb != 0.0) atomicAdd(noise_sum, rb);
        if (rc)        atomicAdd(noise_cnt, (unsigned long long)rc);
    }
}

__global__ void k_alphas(const unsigned long long* __restrict__ packed,
                         const float* __restrict__ x,
                         const float* __restrict__ beta,
                         float4* __restrict__ xa4,
                         float2* __restrict__ qa2,
                         double* __restrict__ coward_sum) {
    int k = blockIdx.x * blockDim.x + threadIdx.x;
    double c = 0.0;
    if (k < NOBJ) {
        unsigned idx = 0xFFFFFFFFu - (unsigned)(packed[k] & 0xFFFFFFFFull);
        const float4* x4 = (const float4*)x;
        float4 A = x4[idx * 3 + 0];
        float4 B = x4[idx * 3 + 1];
        float4 C = x4[idx * 3 + 2];
        xa4[k * 3 + 0] = A;
        xa4[k * 3 + 1] = B;
        xa4[k * 3 + 2] = C;
        float a2 = SS12(A, B, C);
        float b = beta[idx];
        float a = atanhf(b);
        float2 qq; qq.x = a * a + 0.1f; qq.y = a2;
        qa2[k] = qq;
        c = 1.0 - (double)b;
    }
    double rc = waveReduceD(c);
    if ((threadIdx.x & 63) == 0) atomicAdd(coward_sum, rc);
}

// attractive-pair exact pass (v_att + count correction), before k_freq
__global__ void k_att(const float* __restrict__ beta,
                      const float* __restrict__ x,
                      const int* __restrict__ oid,
                      const float4* __restrict__ xa4,
                      const float2* __restrict__ qa2,
                      double* __restrict__ v_att_sum,
                      unsigned long long* __restrict__ att_cnt) {
    int j = blockIdx.x * blockDim.x + threadIdx.x;
    double va = 0.0;
    unsigned int c = 0;
    if (j < NHITS) {
        int o = oid[j];
        if (o > 0) {
            int k = o - 1;
            const float4* x4 = (const float4*)x;
            float4 XA = x4[j * 3 + 0], XB = x4[j * 3 + 1], XC = x4[j * 3 + 2];
            float4 A = xa4[k * 3 + 0], B = xa4[k * 3 + 1], C = xa4[k * 3 + 2];
            float2 Q = qa2[k];
            float dot = DOT12(XA, XB, XC, A, B, C);
            float xx = SS12(XA, XB, XC);
            float d2r = fmaf(-2.0f, dot, xx) + Q.y;
            float a = atanhf(beta[j]);
            float q = a * a + 0.1f;
            va = (double)((q * Q.x) * fmaxf(d2r, 0.0f));
            c = (d2r < 1.0f) ? 1u : 0u;
        }
    }
    double rv = waveReduceD(va);
    unsigned int rc = waveReduceU(c);
    if ((threadIdx.x & 63) == 0) {
        if (rv != 0.0) atomicAdd(v_att_sum, rv);
        if (rc) atomicAdd(att_cnt, (unsigned long long)rc);
    }
}

// attractive-pair sampled-repulsion correction, after k_freq
__global__ void k_att2(const float* __restrict__ beta,
                       const float* __restrict__ x,
                       const int* __restrict__ oid,
                       const float4* __restrict__ xa4,
                       const float2* __restrict__ qa2,
                       const float* __restrict__ freq_ptr,
                       double* __restrict__ v_rep_sum) {
    int j = blockIdx.x * blockDim.x + threadIdx.x;
    double corr = 0.0;
    if (j < NHITS) {
        int o = oid[j];
        if (o > 0) {
            int k = o - 1;
            const float4* x4 = (const float4*)x;
            float4 XA = x4[j * 3 + 0], XB = x4[j * 3 + 1], XC = x4[j * 3 + 2];
            float4 A = xa4[k * 3 + 0], B = xa4[k * 3 + 1], C = xa4[k * 3 + 2];
            float2 Q = qa2[k];
            float dot = DOT12(XA, XB, XC, A, B, C);
            float xx = SS12(XA, XB, XC);
            float d2r = fmaf(-2.0f, dot, xx) + Q.y;
            if (d2r < 1.0f) {
                uint32_t f = (uint32_t)j * NOBJ + (uint32_t)k;
                uint32_t b0, b1, bits;
                if (j < 50000) { threefry2x32(0u, 42u, f, f + HALF_PAIRS, b0, b1); bits = b0; }
                else           { threefry2x32(0u, 42u, f - HALF_PAIRS, f, b0, b1); bits = b1; }
                float u = tf_uniform(bits);
                float freq = *freq_ptr;
                if (u < freq) {
                    float dist = sqrtf(fmaxf(fmaxf(d2r, 0.0f), 1e-12f));
                    float a = atanhf(beta[j]);
                    float q = a * a + 0.1f;
                    corr = -(double)((q * Q.x) * (1.0f - dist));
                }
            }
        }
    }
    double rv = waveReduceD(corr);
    if ((threadIdx.x & 63) == 0) {
        if (rv != 0.0) atomicAdd(v_rep_sum, rv);
    }
}

template <int PASS>
__global__ __launch_bounds__(256)
void k_pairs(const float* __restrict__ x,
             const float* __restrict__ beta,
             const float4* __restrict__ xa4,
             const float2* __restrict__ qa2,
             double* __restrict__ acc_out,
             unsigned long long* __restrict__ nrep_out,
             const float* __restrict__ freq_ptr) {
    __shared__ float4 sxa[KCHUNK * 3];
    __shared__ float2 sqa[KCHUNK];
    __shared__ double sredD[4];
    __shared__ unsigned int sredU[4];

    const int tid = threadIdx.x;
    const int kbase = blockIdx.y * KCHUNK;
    if (tid < KCHUNK * 3) sxa[tid] = xa4[kbase * 3 + tid];
    if (tid < KCHUNK)     sqa[tid] = qa2[kbase + tid];
    __syncthreads();

    const int t = blockIdx.x * 256 + tid;
    const bool valid = t < HQ;
    const int jb = valid ? t : 0;
    const float4* x4 = (const float4*)x;

    float4 X0a = x4[jb * 3 + 0], X0b = x4[jb * 3 + 1], X0c = x4[jb * 3 + 2];
    float4 X1a = x4[(jb + HQ) * 3 + 0], X1b = x4[(jb + HQ) * 3 + 1], X1c = x4[(jb + HQ) * 3 + 2];
    float4 X2a = x4[(jb + 2 * HQ) * 3 + 0], X2b = x4[(jb + 2 * HQ) * 3 + 1], X2c = x4[(jb + 2 * HQ) * 3 + 2];
    float4 X3a = x4[(jb + 3 * HQ) * 3 + 0], X3b = x4[(jb + 3 * HQ) * 3 + 1], X3c = x4[(jb + 3 * HQ) * 3 + 2];

    float inval = valid ? 0.0f : 1e9f;
    float xx0 = SS12(X0a, X0b, X0c) + inval;
    float xx1 = SS12(X1a, X1b, X1c) + inval;
    float xx2 = SS12(X2a, X2b, X2c) + inval;
    float xx3 = SS12(X3a, X3b, X3c) + inval;

    float q0 = 0.f, q1 = 0.f, q2 = 0.f, q3 = 0.f;
    if (PASS == 2) {
        float a0 = atanhf(beta[jb]);
        float a1 = atanhf(beta[jb + HQ]);
        float a2 = atanhf(beta[jb + 2 * HQ]);
        float a3 = atanhf(beta[jb + 3 * HQ]);
        q0 = a0 * a0 + 0.1f; q1 = a1 * a1 + 0.1f;
        q2 = a2 * a2 + 0.1f; q3 = a3 * a3 + 0.1f;
    }

    unsigned int m0 = 0, m1 = 0, m2 = 0, m3 = 0;
    unsigned int bit = 1u;
#pragma unroll 4
    for (int kk = 0; kk < KCHUNK; ++kk) {
        float4 A = sxa[kk * 3 + 0];
        float4 B = sxa[kk * 3 + 1];
        float4 C = sxa[kk * 3 + 2];
        float2 Q = sqa[kk];
        float t0 = fmaf(-2.0f, DOT12(X0a, X0b, X0c, A, B, C), xx0) + Q.y;
        float t1 = fmaf(-2.0f, DOT12(X1a, X1b, X1c, A, B, C), xx1) + Q.y;
        float t2 = fmaf(-2.0f, DOT12(X2a, X2b, X2c, A, B, C), xx2) + Q.y;
        float t3 = fmaf(-2.0f, DOT12(X3a, X3b, X3c, A, B, C), xx3) + Q.y;
        m0 |= (t0 < 1.0f) ? bit : 0u;
        m1 |= (t1 < 1.0f) ? bit : 0u;
        m2 |= (t2 < 1.0f) ? bit : 0u;
        m3 |= (t3 < 1.0f) ? bit : 0u;
        bit += bit;
    }

    if (PASS == 1) {
        unsigned int cnt = (unsigned)(__popc(m0) + __popc(m1) + __popc(m2) + __popc(m3));
        unsigned int rc = waveReduceU(cnt);
        if ((tid & 63) == 0) sredU[tid >> 6] = rc;
        __syncthreads();
        if (tid == 0) {
            unsigned long long s = (unsigned long long)sredU[0] + sredU[1] + sredU[2] + sredU[3];
            if (s) atomicAdd(nrep_out, s);
        }
    } else {
        const float freq = *freq_ptr;
        double acc = 0.0;

#define PROC_SLOT(MASK, SLOT, XA, XB, XC, XX, QH)                                   \
        while (MASK) {                                                              \
            int kk = __ffs(MASK) - 1;                                               \
            MASK &= MASK - 1;                                                       \
            float4 A = sxa[kk * 3 + 0];                                             \
            float4 B = sxa[kk * 3 + 1];                                             \
            float4 C = sxa[kk * 3 + 2];                                             \
            float2 Q = sqa[kk];                                                     \
            float dot = DOT12(XA, XB, XC, A, B, C);                                 \
            float d2r = fmaf(-2.0f, dot, XX) + Q.y;                                 \
            float dist = sqrtf(fmaxf(fmaxf(d2r, 0.0f), 1e-12f));                    \
            uint32_t f = (uint32_t)(jb + (SLOT) * HQ) * NOBJ + (uint32_t)(kbase + kk); \
            uint32_t b0_, b1_, bits;                                                \
            if ((SLOT) < 2) { threefry2x32(0u, 42u, f, f + HALF_PAIRS, b0_, b1_); bits = b0_; } \
            else            { threefry2x32(0u, 42u, f - HALF_PAIRS, f, b0_, b1_); bits = b1_; } \
            float u = tf_uniform(bits);                                             \
            float cv = (u < freq) ? ((QH) * Q.x) * (1.0f - dist) : 0.0f;            \
            acc += (double)cv;                                                      \
        }

        PROC_SLOT(m0, 0, X0a, X0b, X0c, xx0, q0)
        PROC_SLOT(m1, 1, X1a, X1b, X1c, xx1, q1)
        PROC_SLOT(m2, 2, X2a, X2b, X2c, xx2, q2)
        PROC_SLOT(m3, 3, X3a, X3b, X3c, xx3, q3)
#undef PROC_SLOT

        double rv = waveReduceD(acc);
        if ((tid & 63) == 0) sredD[tid >> 6] = rv;
        __syncthreads();
        if (tid == 0) {
            double s = sredD[0] + sredD[1] + sredD[2] + sredD[3];
            if (s != 0.0) atomicAdd(acc_out, s);
        }
    }
}

__global__ void k_freq(const unsigned long long* __restrict__ nrep_all,
                       const unsigned long long* __restrict__ att_cnt,
                       float* __restrict__ freq) {
    unsigned long long n = *nrep_all - *att_cnt;
    if (n < 1ull) n = 1ull;
    float f = 100000.0f / (float)n;
    *freq = fminf(f, 1.0f);
}

__global__ void k_final(const double* __restrict__ accs,
                        const unsigned long long* __restrict__ noise_cnt,
                        const float* __restrict__ freq,
                        float* __restrict__ out) {
    double v_att = accs[0] / (double)NHITS;
    double v_rep = accs[1] / (double)(*freq) / (double)NHITS;
    double l_cow = accs[2] / (double)NOBJ;
    unsigned long long nc = *noise_cnt;
    if (nc < 1ull) nc = 1ull;
    double l_noise = accs[3] / ((double)nc + 1e-9);
    double loss = v_att + v_rep + l_cow + 0.1 * l_noise;
    out[0] = (float)v_att;
    out[1] = (float)v_rep;
    out[2] = (float)l_cow;
    out[3] = (float)l_noise;
    out[4] = (float)loss;
}

// ---------------- launcher ----------------

extern "C" void kernel_launch(void* const* d_in, const int* in_sizes, int n_in,
                              void* d_out, int out_size, void* d_ws, size_t ws_size,
                              hipStream_t stream) {
    const float* beta = (const float*)d_in[0];
    const float* x    = (const float*)d_in[1];
    const int*   oid  = (const int*)d_in[2];
    float* out = (float*)d_out;

    char* ws = (char*)d_ws;
    double* v_att_sum = (double*)(ws + 0);
    double* v_rep_sum = (double*)(ws + 8);
    double* coward_sum = (double*)(ws + 16);
    double* noise_sum = (double*)(ws + 24);
    unsigned long long* noise_cnt = (unsigned long long*)(ws + 32);
    unsigned long long* nrep_all = (unsigned long long*)(ws + 40);
    unsigned long long* att_cnt = (unsigned long long*)(ws + 48);
    float* freq = (float*)(ws + 56);
    unsigned long long* packed = (unsigned long long*)(ws + 64);
    float4* xa4 = (float4*)(ws + 8256);
    float2* qa2 = (float2*)(ws + 57408);

    k_init<<<4, 256, 0, stream>>>(packed, (unsigned long long*)ws);
    k_hits<<<(NHITS + 255) / 256, 256, 0, stream>>>(beta, oid, packed,
                                                    noise_sum, noise_cnt);
    k_alphas<<<4, 256, 0, stream>>>(packed, x, beta, xa4, qa2, coward_sum);

    dim3 gpairs((HQ + 255) / 256, NOBJ / KCHUNK);
    k_pairs<1><<<gpairs, 256, 0, stream>>>(x, beta, xa4, qa2,
                                           nullptr, nrep_all, nullptr);
    k_att<<<(NHITS + 255) / 256, 256, 0, stream>>>(beta, x, oid, xa4, qa2,
                                                   v_att_sum, att_cnt);
    k_freq<<<1, 1, 0, stream>>>(nrep_all, att_cnt, freq);
    k_pairs<2><<<gpairs, 256, 0, stream>>>(x, beta, xa4, qa2,
                                           v_rep_sum, nullptr, freq);
    k_att2<<<(NHITS + 255) / 256, 256, 0, stream>>>(beta, x, oid, xa4, qa2,
                                                    freq, v_rep_sum);
    k_final<<<1, 1, 0, stream>>>((double*)ws, noise_cnt, freq, out);
}

// Round 3
// 162.536 us; speedup vs baseline: 2.2100x; 1.6209x over previous
//
#include <hip/hip_runtime.h>
#include <stdint.h>

#define NHITS 100000
#define NOBJ  1024
#define HALF  50000
#define HALF_PAIRS 51200000u   // NHITS*NOBJ/2

// ---------------- ws layout (bytes) ----------------
// 0:   double v_att_sum
// 8:   double v_rep_sum
// 16:  double coward_sum
// 24:  double noise_sum
// 32:  ull    noise_cnt
// 40:  ull    nrep           (pure repulsive: d2<1 and not attractive)
// 48:  float  freq
// 64:  ull    packed[1024]                         (64..8256)
// 8256: float arec[1024*16] {x[12], qa, a2, 0, 0}  (8256..73792)
// 73792: uint32 maskbuf[32][100000] = 12.8MB       (73792..12873792)

__device__ inline uint32_t rotl32(uint32_t x, int n) {
    return (x << n) | (x >> (32 - n));
}

__device__ inline void threefry2x32(uint32_t k0, uint32_t k1,
                                    uint32_t x0, uint32_t x1,
                                    uint32_t& o0, uint32_t& o1) {
    uint32_t ks2 = k0 ^ k1 ^ 0x1BD11BDAu;
    x0 += k0; x1 += k1;
#define TF_ROUND(r) { x0 += x1; x1 = rotl32(x1, r); x1 ^= x0; }
    TF_ROUND(13) TF_ROUND(15) TF_ROUND(26) TF_ROUND(6)
    x0 += k1;  x1 += ks2 + 1u;
    TF_ROUND(17) TF_ROUND(29) TF_ROUND(16) TF_ROUND(24)
    x0 += ks2; x1 += k0 + 2u;
    TF_ROUND(13) TF_ROUND(15) TF_ROUND(26) TF_ROUND(6)
    x0 += k0;  x1 += k1 + 3u;
    TF_ROUND(17) TF_ROUND(29) TF_ROUND(16) TF_ROUND(24)
    x0 += k1;  x1 += ks2 + 4u;
    TF_ROUND(13) TF_ROUND(15) TF_ROUND(26) TF_ROUND(6)
    x0 += ks2; x1 += k0 + 5u;
#undef TF_ROUND
    o0 = x0; o1 = x1;
}

__device__ inline float tf_uniform(uint32_t bits) {
    return __uint_as_float((bits >> 9) | 0x3f800000u) - 1.0f;
}

__device__ inline double waveReduceD(double v) {
    for (int off = 32; off > 0; off >>= 1) v += __shfl_down(v, off, 64);
    return v;
}
__device__ inline unsigned int waveReduceU(unsigned int v) {
    for (int off = 32; off > 0; off >>= 1) v += __shfl_down(v, off, 64);
    return v;
}

// index of r-th set bit of m (r < popc(m))
__device__ inline int sel32(uint32_t m, int r) {
    int idx = 0;
#pragma unroll
    for (int sh = 16; sh >= 1; sh >>= 1) {
        uint32_t lo = m & ((1u << sh) - 1u);
        int c = __popc(lo);
        if (r >= c) { r -= c; m >>= sh; idx += sh; }
        else { m = lo; }
    }
    return idx;
}

#define DOT12(XA, XB, XC, A, B, C) \
    fmaf((XC).w, (C).w, fmaf((XC).z, (C).z, fmaf((XC).y, (C).y, fmaf((XC).x, (C).x, \
    fmaf((XB).w, (B).w, fmaf((XB).z, (B).z, fmaf((XB).y, (B).y, fmaf((XB).x, (B).x, \
    fmaf((XA).w, (A).w, fmaf((XA).z, (A).z, fmaf((XA).y, (A).y, (XA).x * (A).x)))))))))))

#define SS12(XA, XB, XC) DOT12(XA, XB, XC, XA, XB, XC)

// ---------------- kernels ----------------

__global__ void k_init(unsigned long long* packed, unsigned long long* hdr) {
    int t = blockIdx.x * blockDim.x + threadIdx.x;
    if (t < NOBJ) packed[t] = 0xFFFFFFFFull;
    if (t < 8)    hdr[t] = 0ull;
}

__global__ void k_hits(const float* __restrict__ beta,
                       const int* __restrict__ oid,
                       unsigned long long* __restrict__ packed,
                       double* __restrict__ noise_sum,
                       unsigned long long* __restrict__ noise_cnt) {
    int j = blockIdx.x * blockDim.x + threadIdx.x;
    float nb = 0.0f;
    unsigned int nc = 0;
    if (j < NHITS) {
        float b = beta[j];
        int o = oid[j];
        if (o > 0) {
            float a = atanhf(b);
            float q = a * a + 0.1f;
            unsigned long long p =
                ((unsigned long long)__float_as_uint(q) << 32) |
                (unsigned long long)(0xFFFFFFFFu - (unsigned)j);
            atomicMax(&packed[o - 1], p);
        } else {
            nb = b; nc = 1;
        }
    }
    double rb = waveReduceD((double)nb);
    unsigned int rc = waveReduceU(nc);
    if ((threadIdx.x & 63) == 0) {
        if (rb != 0.0) atomicAdd(noise_sum, rb);
        if (rc)        atomicAdd(noise_cnt, (unsigned long long)rc);
    }
}

__global__ void k_alphas(const unsigned long long* __restrict__ packed,
                         const float* __restrict__ x,
                         const float* __restrict__ beta,
                         float* __restrict__ arec,
                         double* __restrict__ coward_sum) {
    int k = blockIdx.x * blockDim.x + threadIdx.x;
    double c = 0.0;
    if (k < NOBJ) {
        unsigned idx = 0xFFFFFFFFu - (unsigned)(packed[k] & 0xFFFFFFFFull);
        const float4* x4 = (const float4*)x;
        float4 A = x4[idx * 3 + 0];
        float4 B = x4[idx * 3 + 1];
        float4 C = x4[idx * 3 + 2];
        float a2 = SS12(A, B, C);
        float b = beta[idx];
        float a = atanhf(b);
        float4 D; D.x = a * a + 0.1f; D.y = a2; D.z = 0.f; D.w = 0.f;
        float4* ar = (float4*)arec;
        ar[k * 4 + 0] = A;
        ar[k * 4 + 1] = B;
        ar[k * 4 + 2] = C;
        ar[k * 4 + 3] = D;
        c = 1.0 - (double)b;
    }
    double rc = waveReduceD(c);
    if ((threadIdx.x & 63) == 0) atomicAdd(coward_sum, rc);
}

// exact attractive term
__global__ void k_att(const float* __restrict__ beta,
                      const float* __restrict__ x,
                      const int* __restrict__ oid,
                      const float* __restrict__ arec,
                      double* __restrict__ v_att_sum) {
    int j = blockIdx.x * blockDim.x + threadIdx.x;
    double va = 0.0;
    if (j < NHITS) {
        int o = oid[j];
        if (o > 0) {
            int k = o - 1;
            const float4* x4 = (const float4*)x;
            float4 XA = x4[j * 3 + 0], XB = x4[j * 3 + 1], XC = x4[j * 3 + 2];
            const float4* ar = (const float4*)arec;
            float4 A = ar[k * 4 + 0], B = ar[k * 4 + 1], C = ar[k * 4 + 2], D = ar[k * 4 + 3];
            float dot = DOT12(XA, XB, XC, A, B, C);
            float xx = SS12(XA, XB, XC);
            float d2r = fmaf(-2.0f, dot, xx) + D.y;
            float a = atanhf(beta[j]);
            float q = a * a + 0.1f;
            va = (double)((q * D.x) * fmaxf(d2r, 0.0f));
        }
    }
    double rv = waveReduceD(va);
    if ((threadIdx.x & 63) == 0) {
        if (rv != 0.0) atomicAdd(v_att_sum, rv);
    }
}

// single scan: per (hit, object) compute d2<1 & !att mask bits; count; optionally store masks
template <int WRITE>
__global__ __launch_bounds__(256)
void k_scan(const float* __restrict__ x,
            const int* __restrict__ oid,
            const float* __restrict__ arec,
            uint32_t* __restrict__ maskbuf,
            unsigned long long* __restrict__ nrep) {
    int t = blockIdx.x * 256 + threadIdx.x;
    bool valid = t < HALF;
    int j0 = valid ? t : 0;
    int j1 = j0 + HALF;
    const float4* x4 = (const float4*)x;
    float4 X0a = x4[j0 * 3 + 0], X0b = x4[j0 * 3 + 1], X0c = x4[j0 * 3 + 2];
    float4 X1a = x4[j1 * 3 + 0], X1b = x4[j1 * 3 + 1], X1c = x4[j1 * 3 + 2];
    float xx0 = SS12(X0a, X0b, X0c);
    float xx1 = SS12(X1a, X1b, X1c);
    if (!valid) { xx0 = 3e9f; xx1 = 3e9f; }
    int o0 = oid[j0], o1 = oid[j1];
    const float4* ar = (const float4*)arec;

    unsigned int cnt = 0;
#pragma unroll
    for (int g = 0; g < 4; ++g) {
        int kbase = blockIdx.y * 128 + g * 32;
        uint32_t m0 = 0, m1 = 0, bit = 1u;
        for (int kk = 0; kk < 32; ++kk, bit += bit) {
            int k = kbase + kk;
            float4 A = ar[k * 4 + 0];
            float4 B = ar[k * 4 + 1];
            float4 C = ar[k * 4 + 2];
            float4 D = ar[k * 4 + 3];
            float d0 = DOT12(X0a, X0b, X0c, A, B, C);
            float d1 = DOT12(X1a, X1b, X1c, A, B, C);
            float t0 = fmaf(-2.0f, d0, xx0) + D.y;
            float t1 = fmaf(-2.0f, d1, xx1) + D.y;
            m0 |= (t0 < 1.0f && o0 != k + 1) ? bit : 0u;
            m1 |= (t1 < 1.0f && o1 != k + 1) ? bit : 0u;
        }
        cnt += (unsigned)(__popc(m0) + __popc(m1));
        if (WRITE && valid) {
            int K = blockIdx.y * 4 + g;
            maskbuf[(size_t)K * NHITS + j0] = m0;
            maskbuf[(size_t)K * NHITS + j1] = m1;
        }
    }
    unsigned int rc = waveReduceU(cnt);
    __shared__ unsigned int su[4];
    if ((threadIdx.x & 63) == 0) su[threadIdx.x >> 6] = rc;
    __syncthreads();
    if (threadIdx.x == 0) {
        unsigned long long s = (unsigned long long)su[0] + su[1] + su[2] + su[3];
        if (s) atomicAdd(nrep, s);
    }
}

__global__ void k_freq(const unsigned long long* __restrict__ nrep,
                       float* __restrict__ freq) {
    unsigned long long n = *nrep;
    if (n < 1ull) n = 1ull;
    float f = 100000.0f / (float)n;
    *freq = fminf(f, 1.0f);
}

// dense, load-balanced sampled-repulsion pass
template <int RESCAN>
__global__ __launch_bounds__(256)
void k_rep(const float* __restrict__ x,
           const float* __restrict__ beta,
           const int* __restrict__ oid,
           const float* __restrict__ arec,
           const uint32_t* __restrict__ maskbuf,
           const float* __restrict__ freq_ptr,
           double* __restrict__ acc_out) {
    __shared__ float sx[12][257];
    __shared__ float sxa[12][257];
    __shared__ float sxx[256], sq[256], sqa[256], sa2[256];
    __shared__ uint32_t smask[8][256];
    __shared__ uint32_t ssc[256];
    __shared__ uint32_t spfx[257];
    __shared__ double sacc[4];

    const int tid = threadIdx.x;
    const int j = blockIdx.x * 256 + tid;
    const bool jv = j < NHITS;
    const int jc = jv ? j : 0;
    const int kb0 = blockIdx.y * 256;

    const float4* x4 = (const float4*)x;
    float4 XA = x4[jc * 3 + 0], XB = x4[jc * 3 + 1], XC = x4[jc * 3 + 2];
    float xx = SS12(XA, XB, XC);
    {
        float xv[12] = {XA.x, XA.y, XA.z, XA.w, XB.x, XB.y, XB.z, XB.w,
                        XC.x, XC.y, XC.z, XC.w};
#pragma unroll
        for (int d = 0; d < 12; ++d) sx[d][tid] = xv[d];
    }
    sxx[tid] = xx;
    {
        float b = beta[jc];
        float a = atanhf(b);
        sq[tid] = a * a + 0.1f;
    }
    {
        const float4* ar = (const float4*)arec;
        float4 A = ar[(kb0 + tid) * 4 + 0];
        float4 B = ar[(kb0 + tid) * 4 + 1];
        float4 C = ar[(kb0 + tid) * 4 + 2];
        float4 D = ar[(kb0 + tid) * 4 + 3];
        float av[12] = {A.x, A.y, A.z, A.w, B.x, B.y, B.z, B.w,
                        C.x, C.y, C.z, C.w};
#pragma unroll
        for (int d = 0; d < 12; ++d) sxa[d][tid] = av[d];
        sqa[tid] = D.x;
        sa2[tid] = D.y;
    }

    uint32_t mw[8];
    unsigned int cnt = 0;
    if (RESCAN) {
        float xxg = jv ? xx : 3e9f;
        int o = jv ? oid[jc] : -1;
        const float4* ar = (const float4*)arec;
#pragma unroll
        for (int w = 0; w < 8; ++w) {
            uint32_t m = 0, bit = 1u;
            int kbase = kb0 + w * 32;
            for (int kk = 0; kk < 32; ++kk, bit += bit) {
                int k = kbase + kk;
                float4 A = ar[k * 4 + 0];
                float4 B = ar[k * 4 + 1];
                float4 C = ar[k * 4 + 2];
                float4 D = ar[k * 4 + 3];
                float d0 = DOT12(XA, XB, XC, A, B, C);
                float t0 = fmaf(-2.0f, d0, xxg) + D.y;
                m |= (t0 < 1.0f && o != k + 1) ? bit : 0u;
            }
            mw[w] = m;
        }
    } else {
#pragma unroll
        for (int w = 0; w < 8; ++w)
            mw[w] = jv ? maskbuf[(size_t)(blockIdx.y * 8 + w) * NHITS + j] : 0u;
    }
#pragma unroll
    for (int w = 0; w < 8; ++w) {
        smask[w][tid] = mw[w];
        cnt += (unsigned)__popc(mw[w]);
    }

    // block-wide prefix sum (Hillis-Steele)
    ssc[tid] = cnt;
    __syncthreads();
    for (int s = 1; s < 256; s <<= 1) {
        uint32_t v = (tid >= s) ? ssc[tid - s] : 0u;
        __syncthreads();
        ssc[tid] += v;
        __syncthreads();
    }
    if (tid == 0) spfx[0] = 0;
    spfx[tid + 1] = ssc[tid];
    __syncthreads();

    const float freq = *freq_ptr;
    const int B = (int)spfx[256];
    double acc = 0.0;

    for (int r = tid; r < B; r += 256) {
        // find owner thread i: spfx[i] <= r < spfx[i+1]
        int lo = 0, hi = 256;
#pragma unroll
        for (int s = 0; s < 8; ++s) {
            int mid = (lo + hi) >> 1;
            if ((int)spfx[mid] <= r) lo = mid; else hi = mid;
        }
        const int i = lo;
        int rb = r - (int)spfx[i];
        // find word within thread i's 8 mask words
        int w = 0;
        uint32_t word;
        for (;;) {
            word = smask[w][i];
            int c = __popc(word);
            if (rb < c) break;
            rb -= c; ++w;
        }
        const int kk = sel32(word, rb);
        const int kl = w * 32 + kk;
        const int jj = blockIdx.x * 256 + i;
        const int kg = kb0 + kl;

        float dot = sx[0][i] * sxa[0][kl];
#pragma unroll
        for (int d = 1; d < 12; ++d) dot = fmaf(sx[d][i], sxa[d][kl], dot);
        float d2 = fmaf(-2.0f, dot, sxx[i]) + sa2[kl];
        float dist = sqrtf(fmaxf(fmaxf(d2, 0.0f), 1e-12f));

        uint32_t f = (uint32_t)jj * NOBJ + (uint32_t)kg;
        uint32_t b0, b1, bits;
        if (jj < HALF) { threefry2x32(0u, 42u, f, f + HALF_PAIRS, b0, b1); bits = b0; }
        else           { threefry2x32(0u, 42u, f - HALF_PAIRS, f, b0, b1); bits = b1; }
        float u = tf_uniform(bits);
        if (u < freq) {
            float cv = (sq[i] * sqa[kl]) * (1.0f - dist);
            acc += (double)cv;
        }
    }

    double rv = waveReduceD(acc);
    if ((tid & 63) == 0) sacc[tid >> 6] = rv;
    __syncthreads();
    if (tid == 0) {
        double s = sacc[0] + sacc[1] + sacc[2] + sacc[3];
        if (s != 0.0) atomicAdd(acc_out, s);
    }
}

__global__ void k_final(const double* __restrict__ accs,
                        const unsigned long long* __restrict__ noise_cnt,
                        const float* __restrict__ freq,
                        float* __restrict__ out) {
    double v_att = accs[0] / (double)NHITS;
    double v_rep = accs[1] / (double)(*freq) / (double)NHITS;
    double l_cow = accs[2] / (double)NOBJ;
    unsigned long long nc = *noise_cnt;
    if (nc < 1ull) nc = 1ull;
    double l_noise = accs[3] / ((double)nc + 1e-9);
    double loss = v_att + v_rep + l_cow + 0.1 * l_noise;
    out[0] = (float)v_att;
    out[1] = (float)v_rep;
    out[2] = (float)l_cow;
    out[3] = (float)l_noise;
    out[4] = (float)loss;
}

// ---------------- launcher ----------------

extern "C" void kernel_launch(void* const* d_in, const int* in_sizes, int n_in,
                              void* d_out, int out_size, void* d_ws, size_t ws_size,
                              hipStream_t stream) {
    const float* beta = (const float*)d_in[0];
    const float* x    = (const float*)d_in[1];
    const int*   oid  = (const int*)d_in[2];
    float* out = (float*)d_out;

    char* ws = (char*)d_ws;
    double* v_att_sum = (double*)(ws + 0);
    double* v_rep_sum = (double*)(ws + 8);
    double* coward_sum = (double*)(ws + 16);
    double* noise_sum = (double*)(ws + 24);
    unsigned long long* noise_cnt = (unsigned long long*)(ws + 32);
    unsigned long long* nrep = (unsigned long long*)(ws + 40);
    float* freq = (float*)(ws + 48);
    unsigned long long* packed = (unsigned long long*)(ws + 64);
    float* arec = (float*)(ws + 8256);
    uint32_t* maskbuf = (uint32_t*)(ws + 73792);

    const size_t NEED = 73792ull + 32ull * NHITS * 4ull;
    const bool useMask = ws_size >= NEED;

    k_init<<<4, 256, 0, stream>>>(packed, (unsigned long long*)ws);
    k_hits<<<(NHITS + 255) / 256, 256, 0, stream>>>(beta, oid, packed,
                                                    noise_sum, noise_cnt);
    k_alphas<<<4, 256, 0, stream>>>(packed, x, beta, arec, coward_sum);

    dim3 gs((HALF + 255) / 256, 8);
    if (useMask) k_scan<1><<<gs, 256, 0, stream>>>(x, oid, arec, maskbuf, nrep);
    else         k_scan<0><<<gs, 256, 0, stream>>>(x, oid, arec, maskbuf, nrep);

    k_att<<<(NHITS + 255) / 256, 256, 0, stream>>>(beta, x, oid, arec, v_att_sum);
    k_freq<<<1, 1, 0, stream>>>(nrep, freq);

    dim3 gr((NHITS + 255) / 256, 4);
    if (useMask) k_rep<0><<<gr, 256, 0, stream>>>(x, beta, oid, arec, maskbuf,
                                                  freq, v_rep_sum);
    else         k_rep<1><<<gr, 256, 0, stream>>>(x, beta, oid, arec, maskbuf,
                                                  freq, v_rep_sum);

    k_final<<<1, 1, 0, stream>>>((double*)ws, noise_cnt, freq, out);
}